// Round 8
// baseline (145.704 us; speedup 1.0000x reference)
//
#include <hip/hip_runtime.h>
#include <hip/hip_bf16.h>

typedef unsigned short u16;
typedef __bf16 bf16x8 __attribute__((ext_vector_type(8)));
typedef float f32x4 __attribute__((ext_vector_type(4)));
typedef float f32x16 __attribute__((ext_vector_type(16)));
typedef unsigned short u16x8 __attribute__((ext_vector_type(8)));
typedef unsigned short u16x4 __attribute__((ext_vector_type(4)));

// S=128, R=256, CM=256, CZ=128, H=8, HD=32

__device__ __forceinline__ u16 f2bf(float f) {
  union { float f; unsigned u; } v; v.f = f;
  unsigned r = v.u;
  r += 0x7fffu + ((r >> 16) & 1u);   // RNE
  return (u16)(r >> 16);
}
__device__ __forceinline__ float bf2f(u16 u) {
  union { unsigned u; float f; } v; v.u = ((unsigned)u) << 16;
  return v.f;
}

// ---------------------------------------------------------------------------
// Kernel 0: weights fp32 [k][n] -> bf16 packed in MFMA B-fragment order:
// wtp[z][n>>4][k>>5][lane][8]. One fragment = 1KB contiguous.
__global__ __launch_bounds__(256) void k_prep_w(
    const float* __restrict__ wq, const float* __restrict__ wk,
    const float* __restrict__ wv, const float* __restrict__ wg,
    const float* __restrict__ wo, u16* __restrict__ dst) {
  const int widx = blockIdx.x >> 4;
  const int tid = blockIdx.x & 15;
  const int ri = (tid >> 2) * 64;   // k-origin
  const int ci = (tid & 3) * 64;    // n-origin
  const float* src = (widx == 0) ? wq : (widx == 1) ? wk : (widx == 2) ? wv
                    : (widx == 3) ? wg : wo;
  __shared__ float lt[64][68];      // [k][n]
  const int t = threadIdx.x;
  {
    const int r = t >> 2;
    #pragma unroll
    for (int i = 0; i < 4; ++i) {
      const int c = (t & 3) * 16 + i * 4;
      *(float4*)&lt[r][c] = *(const float4*)&src[(ri + r) * 256 + ci + c];
    }
  }
  __syncthreads();
  #pragma unroll
  for (int cc = 0; cc < 2; ++cc) {
    const int c = t + cc * 256;     // chunk 0..511
    const int kb = c >> 8, cb = (c >> 6) & 3, lg = (c >> 4) & 3, lr = c & 15;
    u16x8 o;
    #pragma unroll
    for (int j = 0; j < 8; ++j) o[j] = f2bf(lt[kb * 32 + lg * 8 + j][cb * 16 + lr]);
    const size_t idx = (size_t)widx * 65536 + (size_t)((ci >> 4) + cb) * 4096
                     + (size_t)((ri >> 5) + kb) * 512 + (size_t)(lg * 16 + lr) * 8;
    *(u16x8*)&dst[idx] = o;
  }
}

// ---------------------------------------------------------------------------
// Kernel 1: pair bias -> PERMUTED layout pbp (MFMA-D order). Unchanged.
__global__ __launch_bounds__(256) void k_pair_bias(
    const float* __restrict__ z, const float* __restrict__ zg,
    const float* __restrict__ zb, const float* __restrict__ wz,
    float* __restrict__ pbp) {
  const int t = threadIdx.x;
  const int lane = t & 63, wave = t >> 6;
  const int ql = lane & 15;
  const int p = blockIdx.x * 16 + wave * 4 + (lane >> 4);   // i*256+j
  const float4 zv0 = *(const float4*)(z + (size_t)p * 128 + ql * 8);
  const float4 zv1 = *(const float4*)(z + (size_t)p * 128 + ql * 8 + 4);
  float s = zv0.x + zv0.y + zv0.z + zv0.w + zv1.x + zv1.y + zv1.z + zv1.w;
  float sq = zv0.x * zv0.x + zv0.y * zv0.y + zv0.z * zv0.z + zv0.w * zv0.w
           + zv1.x * zv1.x + zv1.y * zv1.y + zv1.z * zv1.z + zv1.w * zv1.w;
  #pragma unroll
  for (int o = 8; o > 0; o >>= 1) { s += __shfl_xor(s, o); sq += __shfl_xor(sq, o); }
  const float mu = s * 0.0078125f;
  const float var = sq * 0.0078125f - mu * mu;
  const float rs = rsqrtf(var + 1e-5f);
  const int c0 = ql * 8;
  float zn[8];
  zn[0] = (zv0.x - mu) * rs * zg[c0 + 0] + zb[c0 + 0];
  zn[1] = (zv0.y - mu) * rs * zg[c0 + 1] + zb[c0 + 1];
  zn[2] = (zv0.z - mu) * rs * zg[c0 + 2] + zb[c0 + 2];
  zn[3] = (zv0.w - mu) * rs * zg[c0 + 3] + zb[c0 + 3];
  zn[4] = (zv1.x - mu) * rs * zg[c0 + 4] + zb[c0 + 4];
  zn[5] = (zv1.y - mu) * rs * zg[c0 + 5] + zb[c0 + 5];
  zn[6] = (zv1.z - mu) * rs * zg[c0 + 6] + zb[c0 + 6];
  zn[7] = (zv1.w - mu) * rs * zg[c0 + 7] + zb[c0 + 7];
  float a[8] = {};
  #pragma unroll
  for (int i = 0; i < 8; ++i) {
    #pragma unroll
    for (int hh = 0; hh < 8; ++hh) a[hh] += zn[i] * wz[(c0 + i) * 8 + hh];
  }
  #pragma unroll
  for (int hh = 0; hh < 8; ++hh) {
    #pragma unroll
    for (int o = 8; o > 0; o >>= 1) a[hh] += __shfl_xor(a[hh], o);
  }
  if (ql == 0) {
    const int i = p >> 8, j = p & 255;
    const int strip = i >> 5, il = i & 31, jt = j >> 5, r = j & 31;
    const int gh = (r >> 2) & 1, qd = r >> 3, c4 = r & 3;
    const int off = (strip * 8 + jt) * 1024 + (gh * 32 + il) * 16 + qd * 4 + c4;
    #pragma unroll
    for (int hh = 0; hh < 8; ++hh) pbp[(size_t)hh * 65536 + off] = a[hh];
  }
}

// ---------------------------------------------------------------------------
// Kernel 2: LayerNorm(m) -> bf16 [32768][256]. Unchanged.
__global__ __launch_bounds__(256) void k_ln_m(
    const float* __restrict__ m, const float* __restrict__ gam,
    const float* __restrict__ bet, u16* __restrict__ mln) {
  const int lane = threadIdx.x & 63;
  const size_t row = (size_t)blockIdx.x * 4 + (threadIdx.x >> 6);
  const float4 xv = *(const float4*)(m + row * 256 + lane * 4);
  float s = xv.x + xv.y + xv.z + xv.w;
  float sq = xv.x * xv.x + xv.y * xv.y + xv.z * xv.z + xv.w * xv.w;
  #pragma unroll
  for (int o = 32; o > 0; o >>= 1) { s += __shfl_xor(s, o); sq += __shfl_xor(sq, o); }
  const float mu = s * 0.00390625f;
  const float var = sq * 0.00390625f - mu * mu;
  const float rs = rsqrtf(var + 1e-5f);
  const int c = lane * 4;
  u16x4 o4;
  o4.x = f2bf((xv.x - mu) * rs * gam[c] + bet[c]);
  o4.y = f2bf((xv.y - mu) * rs * gam[c + 1] + bet[c + 1]);
  o4.z = f2bf((xv.z - mu) * rs * gam[c + 2] + bet[c + 2]);
  o4.w = f2bf((xv.w - mu) * rs * gam[c + 3] + bet[c + 3]);
  *(u16x4*)(mln + row * 256 + c) = o4;
}

// ---------------------------------------------------------------------------
// Kernel 3 (v6): QKVG. grid (512, 4): block = 64 rows x 256 cols, z = y.
// MFMA loop unchanged from v5. NEW: epilogue routes through LDS (reuse lA)
// so global writes are coalesced: q/k/v = 8 contiguous 4KB per-head regions
// per block (wave-store = 2x512B runs); g = 64B-chunk stores.
__global__ __launch_bounds__(256, 2) void k_qkvg(
    const u16* __restrict__ mln, const u16* __restrict__ wtp,
    const float* __restrict__ bg, u16* __restrict__ q, u16* __restrict__ k,
    u16* __restrict__ v, u16* __restrict__ g) {
  __shared__ u16 lA[64 * 256];
  const int t = threadIdx.x;
  const int z = blockIdx.y;
  const size_t row0 = (size_t)blockIdx.x * 64;
  #pragma unroll
  for (int i = 0; i < 8; ++i) {
    const int r = i * 8 + (t >> 5);
    const int c = (t & 31) * 8;
    *(u16x8*)((char*)lA + ((r * 512 + c * 2) ^ ((r & 7) << 4))) =
        *(const u16x8*)&mln[(row0 + r) * 256 + c];
  }
  __syncthreads();
  const int lane = t & 63, wave = t >> 6;
  const int lrow = lane & 15, lg = lane >> 4;
  const u16* Wz = wtp + (size_t)z * 65536 + (size_t)wave * 16384 + (size_t)lane * 8;
  f32x4 acc[4][4] = {};
  bf16x8 b[3][4];
  #pragma unroll
  for (int nn = 0; nn < 4; ++nn) b[0][nn] = *(const bf16x8*)&Wz[nn * 4096];
  #pragma unroll
  for (int nn = 0; nn < 4; ++nn) b[1][nn] = *(const bf16x8*)&Wz[nn * 4096 + 512];
  #pragma unroll
  for (int kc = 0; kc < 8; ++kc) {
    if (kc < 6) {
      #pragma unroll
      for (int nn = 0; nn < 4; ++nn)
        b[(kc + 2) % 3][nn] = *(const bf16x8*)&Wz[nn * 4096 + (kc + 2) * 512];
    }
    bf16x8 af[4];
    #pragma unroll
    for (int mm = 0; mm < 4; ++mm) {
      const int row = mm * 16 + lrow;
      af[mm] = *(const bf16x8*)((const char*)lA +
          ((row * 512 + kc * 64 + lg * 16) ^ ((row & 7) << 4)));
    }
    const int cur = kc % 3;
    #pragma unroll
    for (int mm = 0; mm < 4; ++mm) {
      #pragma unroll
      for (int nn = 0; nn < 4; ++nn)
        acc[mm][nn] = __builtin_amdgcn_mfma_f32_16x16x32_bf16(
            af[mm], b[cur][nn], acc[mm][nn], 0, 0, 0);
    }
  }
  // ---- epilogue: acc -> LDS (bf16, swizzled) -> coalesced global
  const int wc = wave * 64, lg4 = lg * 4;
  const float scale = (z == 0) ? 0.17677669529663687f : 1.0f;
  __syncthreads();   // all lA reads done before overwrite
  #pragma unroll
  for (int mm = 0; mm < 4; ++mm) {
    #pragma unroll
    for (int nn = 0; nn < 4; ++nn) {
      const int col = wc + nn * 16 + lrow;
      #pragma unroll
      for (int jr = 0; jr < 4; ++jr) {
        const int row = mm * 16 + lg4 + jr;
        const float val = acc[mm][nn][jr];
        u16 o;
        if (z < 3) {
          o = f2bf(val * scale);
        } else {
          const float x = val + bg[col];
          o = f2bf(1.0f / (1.0f + __expf(-x)));
        }
        *(u16*)((char*)lA + ((row * 512 + col * 2) ^ ((row & 7) << 4))) = o;
      }
    }
  }
  __syncthreads();
  if (z < 3) {
    u16* dst = (z == 0) ? q : (z == 1) ? k : v;
    const int si = (int)(row0 >> 8);
    const int ri0 = (int)(row0 & 255);
    const int hh = t >> 5, l5 = t & 31;
    u16* basep = dst + ((size_t)(si * 8 + hh) * 256 + ri0) * 32;
    #pragma unroll
    for (int p = 0; p < 8; ++p) {
      const int chunk = p * 32 + l5;       // 0..255 within this head's 4KB
      const int rr = chunk >> 2;
      const int c8 = (chunk & 3) * 8;
      const u16x8 vv = *(const u16x8*)((const char*)lA +
          ((rr * 512 + (hh * 32 + c8) * 2) ^ ((rr & 7) << 4)));
      *(u16x8*)&basep[chunk * 8] = vv;
    }
  } else {
    const int rr = t >> 2, cb = (t & 3) * 8;
    u16* grow = g + (row0 + rr) * 256;
    #pragma unroll
    for (int i = 0; i < 8; ++i) {
      const int c = cb + i * 32;
      const u16x8 vv = *(const u16x8*)((const char*)lA +
          ((rr * 512 + c * 2) ^ ((rr & 7) << 4)));
      *(u16x8*)&grow[c] = vv;
    }
  }
}

// ---------------------------------------------------------------------------
// Kernel 4: attention, swapped-QK 32x32x16, ONLINE fixed-shift softmax.
// Unchanged from R4.
__global__ __launch_bounds__(256, 4) void k_attn(
    const u16* __restrict__ q, const u16* __restrict__ k,
    const u16* __restrict__ v, const u16* __restrict__ g,
    const float* __restrict__ pbp, const float* __restrict__ mask,
    u16* __restrict__ go) {
  __shared__ u16 lVt[32][276];   // V^T padded
  __shared__ float lMb[256];
  __shared__ float lL[4][32];
  const int bid = blockIdx.x;    // s*8+h
  const int si = bid >> 3, hi = bid & 7;
  const int t = threadIdx.x;
  const size_t base = (size_t)bid * 8192;

  lMb[t] = 1e9f * (mask[si * 256 + t] - 1.0f);
  #pragma unroll
  for (int it = 0; it < 4; ++it) {
    const int r = it * 64 + (t >> 2);
    const int hd0 = (t & 3) * 8;
    u16x8 vv = *(const u16x8*)&v[base + r * 32 + hd0];
    #pragma unroll
    for (int u = 0; u < 8; ++u) lVt[hd0 + u][r] = vv[u];
  }
  __syncthreads();

  const int lane = t & 63, wave = t >> 6;
  const int il = lane & 31, gh = lane >> 5;

  #pragma unroll 1
  for (int strip = 0; strip < 2; ++strip) {
    const int i0 = wave * 64 + strip * 32;
    bf16x8 qf[2];
    #pragma unroll
    for (int kk = 0; kk < 2; ++kk)
      qf[kk] = *(const bf16x8*)&q[base + (size_t)(i0 + il) * 32 + kk * 16 + gh * 8];
    const float* pbt = pbp + ((size_t)hi * 8 + (i0 >> 5)) * 8192 + lane * 16;

    f32x16 oacc0 = {}, oacc1 = {};
    float s0 = 0.f, s1 = 0.f, s2 = 0.f, s3 = 0.f;

    #pragma unroll 2
    for (int jt = 0; jt < 8; ++jt) {
      const float* pl = pbt + jt * 1024;
      // C = pb + mb - 16
      f32x16 c;
      #pragma unroll
      for (int qd = 0; qd < 4; ++qd) {
        const f32x4 pbq = *(const f32x4*)&pl[qd * 4];
        const int jb = jt * 32 + qd * 8 + gh * 4;
        #pragma unroll
        for (int c4 = 0; c4 < 4; ++c4)
          c[qd * 4 + c4] = pbq[c4] + lMb[jb + c4] - 16.0f;
      }
      const bf16x8 kf0 = *(const bf16x8*)&k[base + (size_t)(jt * 32 + il) * 32 + gh * 8];
      const bf16x8 kf1 = *(const bf16x8*)&k[base + (size_t)(jt * 32 + il) * 32 + 16 + gh * 8];
      c = __builtin_amdgcn_mfma_f32_32x32x16_bf16(kf0, qf[0], c, 0, 0, 0);
      c = __builtin_amdgcn_mfma_f32_32x32x16_bf16(kf1, qf[1], c, 0, 0, 0);
      // p = exp(s - 16); partial sums; pack bf16
      union PK { __bf16 h[4]; uint2 u; } pk[4];
      #pragma unroll
      for (int qd = 0; qd < 4; ++qd) {
        const float p0 = __expf(c[qd * 4 + 0]);
        const float p1 = __expf(c[qd * 4 + 1]);
        const float p2 = __expf(c[qd * 4 + 2]);
        const float p3 = __expf(c[qd * 4 + 3]);
        s0 += p0; s1 += p1; s2 += p2; s3 += p3;
        pk[qd].h[0] = (__bf16)p0; pk[qd].h[1] = (__bf16)p1;
        pk[qd].h[2] = (__bf16)p2; pk[qd].h[3] = (__bf16)p3;
      }
      // repack to PV A-fragments via lane^32 exchange
      const uint2 sA = gh ? pk[0].u : pk[1].u;
      uint2 rA; rA.x = __shfl_xor(sA.x, 32); rA.y = __shfl_xor(sA.y, 32);
      const uint2 sB = gh ? pk[2].u : pk[3].u;
      uint2 rB; rB.x = __shfl_xor(sB.x, 32); rB.y = __shfl_xor(sB.y, 32);
      union FR { uint2 u2[2]; bf16x8 v; } fa0, fa1;
      fa0.u2[0] = gh ? rA : pk[0].u;
      fa0.u2[1] = gh ? pk[1].u : rA;
      fa1.u2[0] = gh ? rB : pk[2].u;
      fa1.u2[1] = gh ? pk[3].u : rB;
      const bf16x8 vf0 = *(const bf16x8*)&lVt[il][jt * 32 + gh * 8];
      const bf16x8 vf1 = *(const bf16x8*)&lVt[il][jt * 32 + 16 + gh * 8];
      oacc0 = __builtin_amdgcn_mfma_f32_32x32x16_bf16(fa0.v, vf0, oacc0, 0, 0, 0);
      oacc1 = __builtin_amdgcn_mfma_f32_32x32x16_bf16(fa1.v, vf1, oacc1, 0, 0, 0);
    }

    float lsum = (s0 + s1) + (s2 + s3);
    lsum += __shfl_xor(lsum, 32);
    if (lane < 32) lL[wave][il] = 1.0f / lsum;

    // ---- epilogue: normalize, gate, store
    #pragma unroll
    for (int qd = 0; qd < 4; ++qd) {
      const f32x4 invq = *(const f32x4*)&lL[wave][qd * 8 + gh * 4];
      #pragma unroll
      for (int c4 = 0; c4 < 4; ++c4) {
        const int iloc = qd * 8 + gh * 4 + c4;
        const size_t row = (size_t)si * 256 + i0 + iloc;
        const int col = hi * 32 + il;
        const float ov = (oacc0[qd * 4 + c4] + oacc1[qd * 4 + c4]) * invq[c4];
        go[row * 256 + col] = f2bf(bf2f(g[row * 256 + col]) * ov);
      }
    }
  }
}

// ---------------------------------------------------------------------------
// Kernel 5 (v3): out = go @ wo + bo. grid 1024: 32 rows x 256 cols.
// Unchanged from R7.
__global__ __launch_bounds__(256, 4) void k_gemm_out(
    const u16* __restrict__ go, const u16* __restrict__ wop,
    const float* __restrict__ bo, float* __restrict__ out) {
  __shared__ u16 lA[32 * 256];
  const int t = threadIdx.x;
  const size_t row0 = (size_t)blockIdx.x * 32;
  #pragma unroll
  for (int i = 0; i < 4; ++i) {
    const int r = i * 8 + (t >> 5);
    const int c = (t & 31) * 8;
    *(u16x8*)((char*)lA + ((r * 512 + c * 2) ^ ((r & 7) << 4))) =
        *(const u16x8*)&go[(row0 + r) * 256 + c];
  }
  __syncthreads();
  const int lane = t & 63, wave = t >> 6;
  const int lrow = lane & 15, lg = lane >> 4;
  const u16* Wz = wop + (size_t)wave * 16384 + (size_t)lane * 8;
  f32x4 acc[2][4] = {};
  bf16x8 b[3][4];
  #pragma unroll
  for (int nn = 0; nn < 4; ++nn) b[0][nn] = *(const bf16x8*)&Wz[nn * 4096];
  #pragma unroll
  for (int nn = 0; nn < 4; ++nn) b[1][nn] = *(const bf16x8*)&Wz[nn * 4096 + 512];
  #pragma unroll
  for (int kc = 0; kc < 8; ++kc) {
    if (kc < 6) {
      #pragma unroll
      for (int nn = 0; nn < 4; ++nn)
        b[(kc + 2) % 3][nn] = *(const bf16x8*)&Wz[nn * 4096 + (kc + 2) * 512];
    }
    bf16x8 af[2];
    #pragma unroll
    for (int mm = 0; mm < 2; ++mm) {
      const int row = mm * 16 + lrow;
      af[mm] = *(const bf16x8*)((const char*)lA +
          ((row * 512 + kc * 64 + lg * 16) ^ ((row & 7) << 4)));
    }
    const int cur = kc % 3;
    #pragma unroll
    for (int mm = 0; mm < 2; ++mm) {
      #pragma unroll
      for (int nn = 0; nn < 4; ++nn)
        acc[mm][nn] = __builtin_amdgcn_mfma_f32_16x16x32_bf16(
            af[mm], b[cur][nn], acc[mm][nn], 0, 0, 0);
    }
  }
  const int wc = wave * 64, lg4 = lg * 4;
  #pragma unroll
  for (int mm = 0; mm < 2; ++mm) {
    #pragma unroll
    for (int nn = 0; nn < 4; ++nn) {
      const int col = wc + nn * 16 + lrow;
      #pragma unroll
      for (int jr = 0; jr < 4; ++jr) {
        const size_t row = row0 + mm * 16 + lg4 + jr;
        out[row * 256 + col] = acc[mm][nn][jr] + bo[col];
      }
    }
  }
}

// ---------------------------------------------------------------------------
extern "C" void kernel_launch(void* const* d_in, const int* in_sizes, int n_in,
                              void* d_out, int out_size, void* d_ws, size_t ws_size,
                              hipStream_t stream) {
  const float* m      = (const float*)d_in[0];
  const float* z      = (const float*)d_in[1];
  const float* mask   = (const float*)d_in[2];
  const float* ln_m_g = (const float*)d_in[3];
  const float* ln_m_b = (const float*)d_in[4];
  const float* ln_z_g = (const float*)d_in[5];
  const float* ln_z_b = (const float*)d_in[6];
  const float* w_z    = (const float*)d_in[7];
  const float* wq     = (const float*)d_in[8];
  const float* wk     = (const float*)d_in[9];
  const float* wv     = (const float*)d_in[10];
  const float* wg     = (const float*)d_in[11];
  const float* bg     = (const float*)d_in[12];
  const float* wo     = (const float*)d_in[13];
  const float* bo     = (const float*)d_in[14];
  float* out = (float*)d_out;

  char* w = (char*)d_ws;
  u16* wtp   = (u16*)w;   w += (size_t)5 * 65536 * 2;
  float* pbp = (float*)w; w += (size_t)8 * 65536 * 4;
  u16* mln   = (u16*)w;   w += (size_t)32768 * 256 * 2;
  u16* qw    = (u16*)w;   w += (size_t)32768 * 256 * 2;
  u16* kw    = (u16*)w;   w += (size_t)32768 * 256 * 2;
  u16* vw    = (u16*)w;   w += (size_t)32768 * 256 * 2;
  u16* gw    = (u16*)w;   w += (size_t)32768 * 256 * 2;
  u16* gow   = mln;  // mln dead after k_qkvg; reuse for g*o

  k_prep_w   <<<80, 256, 0, stream>>>(wq, wk, wv, wg, wo, wtp);
  k_pair_bias<<<4096, 256, 0, stream>>>(z, ln_z_g, ln_z_b, w_z, pbp);
  k_ln_m     <<<8192, 256, 0, stream>>>(m, ln_m_g, ln_m_b, mln);
  k_qkvg     <<<dim3(512, 4), 256, 0, stream>>>(mln, wtp, bg, qw, kw, vw, gw);
  k_attn     <<<1024, 256, 0, stream>>>(qw, kw, vw, gw, pbp, mask, gow);
  k_gemm_out <<<1024, 256, 0, stream>>>(gow, wtp + (size_t)4 * 65536, bo, out);
}

// Round 9
// 139.551 us; speedup vs baseline: 1.0441x; 1.0441x over previous
//
#include <hip/hip_runtime.h>
#include <hip/hip_bf16.h>

typedef unsigned short u16;
typedef __bf16 bf16x8 __attribute__((ext_vector_type(8)));
typedef float f32x4 __attribute__((ext_vector_type(4)));
typedef float f32x16 __attribute__((ext_vector_type(16)));
typedef unsigned short u16x8 __attribute__((ext_vector_type(8)));
typedef unsigned short u16x4 __attribute__((ext_vector_type(4)));

// S=128, R=256, CM=256, CZ=128, H=8, HD=32

__device__ __forceinline__ u16 f2bf(float f) {
  union { float f; unsigned u; } v; v.f = f;
  unsigned r = v.u;
  r += 0x7fffu + ((r >> 16) & 1u);   // RNE
  return (u16)(r >> 16);
}
__device__ __forceinline__ float bf2f(u16 u) {
  union { unsigned u; float f; } v; v.u = ((unsigned)u) << 16;
  return v.f;
}

// ---------------------------------------------------------------------------
// Kernel 0: weights fp32 [k][n] -> bf16 packed in MFMA B-fragment order:
// wtp[z][n>>4][k>>5][lane][8]. One fragment = 1KB contiguous.
__global__ __launch_bounds__(256) void k_prep_w(
    const float* __restrict__ wq, const float* __restrict__ wk,
    const float* __restrict__ wv, const float* __restrict__ wg,
    const float* __restrict__ wo, u16* __restrict__ dst) {
  const int widx = blockIdx.x >> 4;
  const int tid = blockIdx.x & 15;
  const int ri = (tid >> 2) * 64;   // k-origin
  const int ci = (tid & 3) * 64;    // n-origin
  const float* src = (widx == 0) ? wq : (widx == 1) ? wk : (widx == 2) ? wv
                    : (widx == 3) ? wg : wo;
  __shared__ float lt[64][68];      // [k][n]
  const int t = threadIdx.x;
  {
    const int r = t >> 2;
    #pragma unroll
    for (int i = 0; i < 4; ++i) {
      const int c = (t & 3) * 16 + i * 4;
      *(float4*)&lt[r][c] = *(const float4*)&src[(ri + r) * 256 + ci + c];
    }
  }
  __syncthreads();
  #pragma unroll
  for (int cc = 0; cc < 2; ++cc) {
    const int c = t + cc * 256;     // chunk 0..511
    const int kb = c >> 8, cb = (c >> 6) & 3, lg = (c >> 4) & 3, lr = c & 15;
    u16x8 o;
    #pragma unroll
    for (int j = 0; j < 8; ++j) o[j] = f2bf(lt[kb * 32 + lg * 8 + j][cb * 16 + lr]);
    const size_t idx = (size_t)widx * 65536 + (size_t)((ci >> 4) + cb) * 4096
                     + (size_t)((ri >> 5) + kb) * 512 + (size_t)(lg * 16 + lr) * 8;
    *(u16x8*)&dst[idx] = o;
  }
}

// ---------------------------------------------------------------------------
// Kernel 1: pair bias -> PERMUTED layout pbp (MFMA-D order). Unchanged.
__global__ __launch_bounds__(256) void k_pair_bias(
    const float* __restrict__ z, const float* __restrict__ zg,
    const float* __restrict__ zb, const float* __restrict__ wz,
    float* __restrict__ pbp) {
  const int t = threadIdx.x;
  const int lane = t & 63, wave = t >> 6;
  const int ql = lane & 15;
  const int p = blockIdx.x * 16 + wave * 4 + (lane >> 4);   // i*256+j
  const float4 zv0 = *(const float4*)(z + (size_t)p * 128 + ql * 8);
  const float4 zv1 = *(const float4*)(z + (size_t)p * 128 + ql * 8 + 4);
  float s = zv0.x + zv0.y + zv0.z + zv0.w + zv1.x + zv1.y + zv1.z + zv1.w;
  float sq = zv0.x * zv0.x + zv0.y * zv0.y + zv0.z * zv0.z + zv0.w * zv0.w
           + zv1.x * zv1.x + zv1.y * zv1.y + zv1.z * zv1.z + zv1.w * zv1.w;
  #pragma unroll
  for (int o = 8; o > 0; o >>= 1) { s += __shfl_xor(s, o); sq += __shfl_xor(sq, o); }
  const float mu = s * 0.0078125f;
  const float var = sq * 0.0078125f - mu * mu;
  const float rs = rsqrtf(var + 1e-5f);
  const int c0 = ql * 8;
  float zn[8];
  zn[0] = (zv0.x - mu) * rs * zg[c0 + 0] + zb[c0 + 0];
  zn[1] = (zv0.y - mu) * rs * zg[c0 + 1] + zb[c0 + 1];
  zn[2] = (zv0.z - mu) * rs * zg[c0 + 2] + zb[c0 + 2];
  zn[3] = (zv0.w - mu) * rs * zg[c0 + 3] + zb[c0 + 3];
  zn[4] = (zv1.x - mu) * rs * zg[c0 + 4] + zb[c0 + 4];
  zn[5] = (zv1.y - mu) * rs * zg[c0 + 5] + zb[c0 + 5];
  zn[6] = (zv1.z - mu) * rs * zg[c0 + 6] + zb[c0 + 6];
  zn[7] = (zv1.w - mu) * rs * zg[c0 + 7] + zb[c0 + 7];
  float a[8] = {};
  #pragma unroll
  for (int i = 0; i < 8; ++i) {
    #pragma unroll
    for (int hh = 0; hh < 8; ++hh) a[hh] += zn[i] * wz[(c0 + i) * 8 + hh];
  }
  #pragma unroll
  for (int hh = 0; hh < 8; ++hh) {
    #pragma unroll
    for (int o = 8; o > 0; o >>= 1) a[hh] += __shfl_xor(a[hh], o);
  }
  if (ql == 0) {
    const int i = p >> 8, j = p & 255;
    const int strip = i >> 5, il = i & 31, jt = j >> 5, r = j & 31;
    const int gh = (r >> 2) & 1, qd = r >> 3, c4 = r & 3;
    const int off = (strip * 8 + jt) * 1024 + (gh * 32 + il) * 16 + qd * 4 + c4;
    #pragma unroll
    for (int hh = 0; hh < 8; ++hh) pbp[(size_t)hh * 65536 + off] = a[hh];
  }
}

// ---------------------------------------------------------------------------
// Kernel 2: LayerNorm(m) -> bf16 [32768][256]. Unchanged.
__global__ __launch_bounds__(256) void k_ln_m(
    const float* __restrict__ m, const float* __restrict__ gam,
    const float* __restrict__ bet, u16* __restrict__ mln) {
  const int lane = threadIdx.x & 63;
  const size_t row = (size_t)blockIdx.x * 4 + (threadIdx.x >> 6);
  const float4 xv = *(const float4*)(m + row * 256 + lane * 4);
  float s = xv.x + xv.y + xv.z + xv.w;
  float sq = xv.x * xv.x + xv.y * xv.y + xv.z * xv.z + xv.w * xv.w;
  #pragma unroll
  for (int o = 32; o > 0; o >>= 1) { s += __shfl_xor(s, o); sq += __shfl_xor(sq, o); }
  const float mu = s * 0.00390625f;
  const float var = sq * 0.00390625f - mu * mu;
  const float rs = rsqrtf(var + 1e-5f);
  const int c = lane * 4;
  u16x4 o4;
  o4.x = f2bf((xv.x - mu) * rs * gam[c] + bet[c]);
  o4.y = f2bf((xv.y - mu) * rs * gam[c + 1] + bet[c + 1]);
  o4.z = f2bf((xv.z - mu) * rs * gam[c + 2] + bet[c + 2]);
  o4.w = f2bf((xv.w - mu) * rs * gam[c + 3] + bet[c + 3]);
  *(u16x4*)(mln + row * 256 + c) = o4;
}

// ---------------------------------------------------------------------------
// Kernel 3 (v7): QKVG. grid (512, 4): block = 64 rows x 256 cols, z = y.
// FIX: B preloaded in 4-kc half-batches of 16 fragments (64 VGPR), issue
// points pinned with sched_barrier(0) so the compiler cannot sink them.
// B0 issued before __syncthreads -> latency hides under A-stage drain.
__global__ __launch_bounds__(256, 3) void k_qkvg(
    const u16* __restrict__ mln, const u16* __restrict__ wtp,
    const float* __restrict__ bg, u16* __restrict__ q, u16* __restrict__ k,
    u16* __restrict__ v, u16* __restrict__ g) {
  __shared__ u16 lA[64 * 256];
  const int t = threadIdx.x;
  const int z = blockIdx.y;
  const size_t row0 = (size_t)blockIdx.x * 64;
  const int lane = t & 63, wave = t >> 6;
  const u16* Wz = wtp + (size_t)z * 65536 + (size_t)wave * 16384 + (size_t)lane * 8;
  // issue A loads
  u16x8 areg[8];
  #pragma unroll
  for (int i = 0; i < 8; ++i)
    areg[i] = *(const u16x8*)&mln[(row0 + i * 8 + (t >> 5)) * 256 + (t & 31) * 8];
  // issue B half 0 (kc 0..3) - independent of LDS, overlaps stage drain
  bf16x8 B[4][4];
  #pragma unroll
  for (int kc = 0; kc < 4; ++kc) {
    #pragma unroll
    for (int nn = 0; nn < 4; ++nn)
      B[kc][nn] = *(const bf16x8*)&Wz[nn * 4096 + kc * 512];
  }
  __builtin_amdgcn_sched_barrier(0);   // pin issue point: no sinking
  // LDS write A (swizzled, conflict-free octets)
  #pragma unroll
  for (int i = 0; i < 8; ++i) {
    const int r = i * 8 + (t >> 5);
    const int c = (t & 31) * 8;
    *(u16x8*)((char*)lA + ((r * 512 + c * 2) ^ ((r & 7) << 4))) = areg[i];
  }
  __syncthreads();
  const int lrow = lane & 15, lg = lane >> 4;
  f32x4 acc[4][4] = {};
  // ---- pass 0: kc 0..3 (B in registers)
  #pragma unroll
  for (int kc = 0; kc < 4; ++kc) {
    bf16x8 af[4];
    #pragma unroll
    for (int mm = 0; mm < 4; ++mm) {
      const int row = mm * 16 + lrow;
      af[mm] = *(const bf16x8*)((const char*)lA +
          ((row * 512 + kc * 64 + lg * 16) ^ ((row & 7) << 4)));
    }
    #pragma unroll
    for (int mm = 0; mm < 4; ++mm) {
      #pragma unroll
      for (int nn = 0; nn < 4; ++nn)
        acc[mm][nn] = __builtin_amdgcn_mfma_f32_16x16x32_bf16(
            af[mm], B[kc][nn], acc[mm][nn], 0, 0, 0);
    }
  }
  // ---- issue B half 1 (kc 4..7), pinned
  #pragma unroll
  for (int kc = 0; kc < 4; ++kc) {
    #pragma unroll
    for (int nn = 0; nn < 4; ++nn)
      B[kc][nn] = *(const bf16x8*)&Wz[nn * 4096 + (kc + 4) * 512];
  }
  __builtin_amdgcn_sched_barrier(0);
  // ---- pass 1: kc 4..7
  #pragma unroll
  for (int kc = 0; kc < 4; ++kc) {
    bf16x8 af[4];
    #pragma unroll
    for (int mm = 0; mm < 4; ++mm) {
      const int row = mm * 16 + lrow;
      af[mm] = *(const bf16x8*)((const char*)lA +
          ((row * 512 + (kc + 4) * 64 + lg * 16) ^ ((row & 7) << 4)));
    }
    #pragma unroll
    for (int mm = 0; mm < 4; ++mm) {
      #pragma unroll
      for (int nn = 0; nn < 4; ++nn)
        acc[mm][nn] = __builtin_amdgcn_mfma_f32_16x16x32_bf16(
            af[mm], B[kc][nn], acc[mm][nn], 0, 0, 0);
    }
  }
  // ---- epilogue: acc -> LDS (bf16, swizzled) -> coalesced global
  const int wc = wave * 64, lg4 = lg * 4;
  const float scale = (z == 0) ? 0.17677669529663687f : 1.0f;
  __syncthreads();   // all lA reads done before overwrite
  #pragma unroll
  for (int mm = 0; mm < 4; ++mm) {
    #pragma unroll
    for (int nn = 0; nn < 4; ++nn) {
      const int col = wc + nn * 16 + lrow;
      #pragma unroll
      for (int jr = 0; jr < 4; ++jr) {
        const int row = mm * 16 + lg4 + jr;
        const float val = acc[mm][nn][jr];
        u16 o;
        if (z < 3) {
          o = f2bf(val * scale);
        } else {
          const float x = val + bg[col];
          o = f2bf(1.0f / (1.0f + __expf(-x)));
        }
        *(u16*)((char*)lA + ((row * 512 + col * 2) ^ ((row & 7) << 4))) = o;
      }
    }
  }
  __syncthreads();
  if (z < 3) {
    u16* dst = (z == 0) ? q : (z == 1) ? k : v;
    const int si = (int)(row0 >> 8);
    const int ri0 = (int)(row0 & 255);
    const int hh = t >> 5, l5 = t & 31;
    u16* basep = dst + ((size_t)(si * 8 + hh) * 256 + ri0) * 32;
    #pragma unroll
    for (int p = 0; p < 8; ++p) {
      const int chunk = p * 32 + l5;       // 0..255 within this head's 4KB
      const int rr = chunk >> 2;
      const int c8 = (chunk & 3) * 8;
      const u16x8 vv = *(const u16x8*)((const char*)lA +
          ((rr * 512 + (hh * 32 + c8) * 2) ^ ((rr & 7) << 4)));
      *(u16x8*)&basep[chunk * 8] = vv;
    }
  } else {
    const int rr = t >> 2, cb = (t & 3) * 8;
    u16* grow = g + (row0 + rr) * 256;
    #pragma unroll
    for (int i = 0; i < 8; ++i) {
      const int c = cb + i * 32;
      const u16x8 vv = *(const u16x8*)((const char*)lA +
          ((rr * 512 + c * 2) ^ ((rr & 7) << 4)));
      *(u16x8*)&grow[c] = vv;
    }
  }
}

// ---------------------------------------------------------------------------
// Kernel 4: attention, swapped-QK 32x32x16, ONLINE fixed-shift softmax.
// Unchanged from R4.
__global__ __launch_bounds__(256, 4) void k_attn(
    const u16* __restrict__ q, const u16* __restrict__ k,
    const u16* __restrict__ v, const u16* __restrict__ g,
    const float* __restrict__ pbp, const float* __restrict__ mask,
    u16* __restrict__ go) {
  __shared__ u16 lVt[32][276];   // V^T padded
  __shared__ float lMb[256];
  __shared__ float lL[4][32];
  const int bid = blockIdx.x;    // s*8+h
  const int si = bid >> 3, hi = bid & 7;
  const int t = threadIdx.x;
  const size_t base = (size_t)bid * 8192;

  lMb[t] = 1e9f * (mask[si * 256 + t] - 1.0f);
  #pragma unroll
  for (int it = 0; it < 4; ++it) {
    const int r = it * 64 + (t >> 2);
    const int hd0 = (t & 3) * 8;
    u16x8 vv = *(const u16x8*)&v[base + r * 32 + hd0];
    #pragma unroll
    for (int u = 0; u < 8; ++u) lVt[hd0 + u][r] = vv[u];
  }
  __syncthreads();

  const int lane = t & 63, wave = t >> 6;
  const int il = lane & 31, gh = lane >> 5;

  #pragma unroll 1
  for (int strip = 0; strip < 2; ++strip) {
    const int i0 = wave * 64 + strip * 32;
    bf16x8 qf[2];
    #pragma unroll
    for (int kk = 0; kk < 2; ++kk)
      qf[kk] = *(const bf16x8*)&q[base + (size_t)(i0 + il) * 32 + kk * 16 + gh * 8];
    const float* pbt = pbp + ((size_t)hi * 8 + (i0 >> 5)) * 8192 + lane * 16;

    f32x16 oacc0 = {}, oacc1 = {};
    float s0 = 0.f, s1 = 0.f, s2 = 0.f, s3 = 0.f;

    #pragma unroll 2
    for (int jt = 0; jt < 8; ++jt) {
      const float* pl = pbt + jt * 1024;
      // C = pb + mb - 16
      f32x16 c;
      #pragma unroll
      for (int qd = 0; qd < 4; ++qd) {
        const f32x4 pbq = *(const f32x4*)&pl[qd * 4];
        const int jb = jt * 32 + qd * 8 + gh * 4;
        #pragma unroll
        for (int c4 = 0; c4 < 4; ++c4)
          c[qd * 4 + c4] = pbq[c4] + lMb[jb + c4] - 16.0f;
      }
      const bf16x8 kf0 = *(const bf16x8*)&k[base + (size_t)(jt * 32 + il) * 32 + gh * 8];
      const bf16x8 kf1 = *(const bf16x8*)&k[base + (size_t)(jt * 32 + il) * 32 + 16 + gh * 8];
      c = __builtin_amdgcn_mfma_f32_32x32x16_bf16(kf0, qf[0], c, 0, 0, 0);
      c = __builtin_amdgcn_mfma_f32_32x32x16_bf16(kf1, qf[1], c, 0, 0, 0);
      // p = exp(s - 16); partial sums; pack bf16
      union PK { __bf16 h[4]; uint2 u; } pk[4];
      #pragma unroll
      for (int qd = 0; qd < 4; ++qd) {
        const float p0 = __expf(c[qd * 4 + 0]);
        const float p1 = __expf(c[qd * 4 + 1]);
        const float p2 = __expf(c[qd * 4 + 2]);
        const float p3 = __expf(c[qd * 4 + 3]);
        s0 += p0; s1 += p1; s2 += p2; s3 += p3;
        pk[qd].h[0] = (__bf16)p0; pk[qd].h[1] = (__bf16)p1;
        pk[qd].h[2] = (__bf16)p2; pk[qd].h[3] = (__bf16)p3;
      }
      // repack to PV A-fragments via lane^32 exchange
      const uint2 sA = gh ? pk[0].u : pk[1].u;
      uint2 rA; rA.x = __shfl_xor(sA.x, 32); rA.y = __shfl_xor(sA.y, 32);
      const uint2 sB = gh ? pk[2].u : pk[3].u;
      uint2 rB; rB.x = __shfl_xor(sB.x, 32); rB.y = __shfl_xor(sB.y, 32);
      union FR { uint2 u2[2]; bf16x8 v; } fa0, fa1;
      fa0.u2[0] = gh ? rA : pk[0].u;
      fa0.u2[1] = gh ? pk[1].u : rA;
      fa1.u2[0] = gh ? rB : pk[2].u;
      fa1.u2[1] = gh ? pk[3].u : rB;
      const bf16x8 vf0 = *(const bf16x8*)&lVt[il][jt * 32 + gh * 8];
      const bf16x8 vf1 = *(const bf16x8*)&lVt[il][jt * 32 + 16 + gh * 8];
      oacc0 = __builtin_amdgcn_mfma_f32_32x32x16_bf16(fa0.v, vf0, oacc0, 0, 0, 0);
      oacc1 = __builtin_amdgcn_mfma_f32_32x32x16_bf16(fa1.v, vf1, oacc1, 0, 0, 0);
    }

    float lsum = (s0 + s1) + (s2 + s3);
    lsum += __shfl_xor(lsum, 32);
    if (lane < 32) lL[wave][il] = 1.0f / lsum;

    // ---- epilogue: normalize, gate, store
    #pragma unroll
    for (int qd = 0; qd < 4; ++qd) {
      const f32x4 invq = *(const f32x4*)&lL[wave][qd * 8 + gh * 4];
      #pragma unroll
      for (int c4 = 0; c4 < 4; ++c4) {
        const int iloc = qd * 8 + gh * 4 + c4;
        const size_t row = (size_t)si * 256 + i0 + iloc;
        const int col = hi * 32 + il;
        const float ov = (oacc0[qd * 4 + c4] + oacc1[qd * 4 + c4]) * invq[c4];
        go[row * 256 + col] = f2bf(bf2f(g[row * 256 + col]) * ov);
      }
    }
  }
}

// ---------------------------------------------------------------------------
// Kernel 5 (v4): out = go @ wo + bo. grid 1024: 32 rows x 256 cols.
// Same B-half-preload + sched_barrier treatment as k_qkvg.
__global__ __launch_bounds__(256, 4) void k_gemm_out(
    const u16* __restrict__ go, const u16* __restrict__ wop,
    const float* __restrict__ bo, float* __restrict__ out) {
  __shared__ u16 lA[32 * 256];
  const int t = threadIdx.x;
  const size_t row0 = (size_t)blockIdx.x * 32;
  const int lane = t & 63, wave = t >> 6;
  const u16* Wz = wop + (size_t)wave * 16384 + (size_t)lane * 8;
  u16x8 areg[4];
  #pragma unroll
  for (int i = 0; i < 4; ++i)
    areg[i] = *(const u16x8*)&go[(row0 + i * 8 + (t >> 5)) * 256 + (t & 31) * 8];
  bf16x8 B[4][4];
  #pragma unroll
  for (int kc = 0; kc < 4; ++kc) {
    #pragma unroll
    for (int nn = 0; nn < 4; ++nn)
      B[kc][nn] = *(const bf16x8*)&Wz[nn * 4096 + kc * 512];
  }
  __builtin_amdgcn_sched_barrier(0);
  #pragma unroll
  for (int i = 0; i < 4; ++i) {
    const int r = i * 8 + (t >> 5);
    const int c = (t & 31) * 8;
    *(u16x8*)((char*)lA + ((r * 512 + c * 2) ^ ((r & 7) << 4))) = areg[i];
  }
  __syncthreads();
  const int lrow = lane & 15, lg = lane >> 4;
  f32x4 acc[2][4] = {};
  #pragma unroll
  for (int kc = 0; kc < 4; ++kc) {
    bf16x8 af[2];
    #pragma unroll
    for (int mm = 0; mm < 2; ++mm) {
      const int row = mm * 16 + lrow;
      af[mm] = *(const bf16x8*)((const char*)lA +
          ((row * 512 + kc * 64 + lg * 16) ^ ((row & 7) << 4)));
    }
    #pragma unroll
    for (int mm = 0; mm < 2; ++mm) {
      #pragma unroll
      for (int nn = 0; nn < 4; ++nn)
        acc[mm][nn] = __builtin_amdgcn_mfma_f32_16x16x32_bf16(
            af[mm], B[kc][nn], acc[mm][nn], 0, 0, 0);
    }
  }
  #pragma unroll
  for (int kc = 0; kc < 4; ++kc) {
    #pragma unroll
    for (int nn = 0; nn < 4; ++nn)
      B[kc][nn] = *(const bf16x8*)&Wz[nn * 4096 + (kc + 4) * 512];
  }
  __builtin_amdgcn_sched_barrier(0);
  #pragma unroll
  for (int kc = 0; kc < 4; ++kc) {
    bf16x8 af[2];
    #pragma unroll
    for (int mm = 0; mm < 2; ++mm) {
      const int row = mm * 16 + lrow;
      af[mm] = *(const bf16x8*)((const char*)lA +
          ((row * 512 + (kc + 4) * 64 + lg * 16) ^ ((row & 7) << 4)));
    }
    #pragma unroll
    for (int mm = 0; mm < 2; ++mm) {
      #pragma unroll
      for (int nn = 0; nn < 4; ++nn)
        acc[mm][nn] = __builtin_amdgcn_mfma_f32_16x16x32_bf16(
            af[mm], B[kc][nn], acc[mm][nn], 0, 0, 0);
    }
  }
  const int wc = wave * 64, lg4 = lg * 4;
  #pragma unroll
  for (int mm = 0; mm < 2; ++mm) {
    #pragma unroll
    for (int nn = 0; nn < 4; ++nn) {
      const int col = wc + nn * 16 + lrow;
      #pragma unroll
      for (int jr = 0; jr < 4; ++jr) {
        const size_t row = row0 + mm * 16 + lg4 + jr;
        out[row * 256 + col] = acc[mm][nn][jr] + bo[col];
      }
    }
  }
}

// ---------------------------------------------------------------------------
extern "C" void kernel_launch(void* const* d_in, const int* in_sizes, int n_in,
                              void* d_out, int out_size, void* d_ws, size_t ws_size,
                              hipStream_t stream) {
  const float* m      = (const float*)d_in[0];
  const float* z      = (const float*)d_in[1];
  const float* mask   = (const float*)d_in[2];
  const float* ln_m_g = (const float*)d_in[3];
  const float* ln_m_b = (const float*)d_in[4];
  const float* ln_z_g = (const float*)d_in[5];
  const float* ln_z_b = (const float*)d_in[6];
  const float* w_z    = (const float*)d_in[7];
  const float* wq     = (const float*)d_in[8];
  const float* wk     = (const float*)d_in[9];
  const float* wv     = (const float*)d_in[10];
  const float* wg     = (const float*)d_in[11];
  const float* bg     = (const float*)d_in[12];
  const float* wo     = (const float*)d_in[13];
  const float* bo     = (const float*)d_in[14];
  float* out = (float*)d_out;

  char* w = (char*)d_ws;
  u16* wtp   = (u16*)w;   w += (size_t)5 * 65536 * 2;
  float* pbp = (float*)w; w += (size_t)8 * 65536 * 4;
  u16* mln   = (u16*)w;   w += (size_t)32768 * 256 * 2;
  u16* qw    = (u16*)w;   w += (size_t)32768 * 256 * 2;
  u16* kw    = (u16*)w;   w += (size_t)32768 * 256 * 2;
  u16* vw    = (u16*)w;   w += (size_t)32768 * 256 * 2;
  u16* gw    = (u16*)w;   w += (size_t)32768 * 256 * 2;
  u16* gow   = mln;  // mln dead after k_qkvg; reuse for g*o

  k_prep_w   <<<80, 256, 0, stream>>>(wq, wk, wv, wg, wo, wtp);
  k_pair_bias<<<4096, 256, 0, stream>>>(z, ln_z_g, ln_z_b, w_z, pbp);
  k_ln_m     <<<8192, 256, 0, stream>>>(m, ln_m_g, ln_m_b, mln);
  k_qkvg     <<<dim3(512, 4), 256, 0, stream>>>(mln, wtp, bg, qw, kw, vw, gw);
  k_attn     <<<1024, 256, 0, stream>>>(qw, kw, vw, gw, pbp, mask, gow);
  k_gemm_out <<<1024, 256, 0, stream>>>(gow, wtp + (size_t)4 * 65536, bo, out);
}

// Round 11
// 122.896 us; speedup vs baseline: 1.1856x; 1.1355x over previous
//
#include <hip/hip_runtime.h>
#include <hip/hip_bf16.h>

typedef unsigned short u16;
typedef __bf16 bf16x8 __attribute__((ext_vector_type(8)));
typedef float f32x4 __attribute__((ext_vector_type(4)));
typedef float f32x16 __attribute__((ext_vector_type(16)));
typedef unsigned short u16x8 __attribute__((ext_vector_type(8)));
typedef unsigned short u16x4 __attribute__((ext_vector_type(4)));

// S=128, R=256, CM=256, CZ=128, H=8, HD=32

__device__ __forceinline__ u16 f2bf(float f) {
  union { float f; unsigned u; } v; v.f = f;
  unsigned r = v.u;
  r += 0x7fffu + ((r >> 16) & 1u);   // RNE
  return (u16)(r >> 16);
}
__device__ __forceinline__ float bf2f(u16 u) {
  union { unsigned u; float f; } v; v.u = ((unsigned)u) << 16;
  return v.f;
}

// ---------------------------------------------------------------------------
// Kernel 0: weights fp32 [k][n] -> bf16 packed in MFMA B-fragment order:
// wtp[z][n>>4][k>>5][(k_sub>>3)*16 + (n&15)][k&7]. One fragment = 1KB contig.
__global__ __launch_bounds__(256) void k_prep_w(
    const float* __restrict__ wq, const float* __restrict__ wk,
    const float* __restrict__ wv, const float* __restrict__ wg,
    const float* __restrict__ wo, u16* __restrict__ dst) {
  const int widx = blockIdx.x >> 4;
  const int tid = blockIdx.x & 15;
  const int ri = (tid >> 2) * 64;   // k-origin
  const int ci = (tid & 3) * 64;    // n-origin
  const float* src = (widx == 0) ? wq : (widx == 1) ? wk : (widx == 2) ? wv
                    : (widx == 3) ? wg : wo;
  __shared__ float lt[64][68];      // [k][n]
  const int t = threadIdx.x;
  {
    const int r = t >> 2;
    #pragma unroll
    for (int i = 0; i < 4; ++i) {
      const int c = (t & 3) * 16 + i * 4;
      *(float4*)&lt[r][c] = *(const float4*)&src[(ri + r) * 256 + ci + c];
    }
  }
  __syncthreads();
  #pragma unroll
  for (int cc = 0; cc < 2; ++cc) {
    const int c = t + cc * 256;     // chunk 0..511
    const int kb = c >> 8, cb = (c >> 6) & 3, lg = (c >> 4) & 3, lr = c & 15;
    u16x8 o;
    #pragma unroll
    for (int j = 0; j < 8; ++j) o[j] = f2bf(lt[kb * 32 + lg * 8 + j][cb * 16 + lr]);
    const size_t idx = (size_t)widx * 65536 + (size_t)((ci >> 4) + cb) * 4096
                     + (size_t)((ri >> 5) + kb) * 512 + (size_t)(lg * 16 + lr) * 8;
    *(u16x8*)&dst[idx] = o;
  }
}

// ---------------------------------------------------------------------------
// Kernel 1: pair bias -> PERMUTED layout pbp (MFMA-D order). Unchanged.
__global__ __launch_bounds__(256) void k_pair_bias(
    const float* __restrict__ z, const float* __restrict__ zg,
    const float* __restrict__ zb, const float* __restrict__ wz,
    float* __restrict__ pbp) {
  const int t = threadIdx.x;
  const int lane = t & 63, wave = t >> 6;
  const int ql = lane & 15;
  const int p = blockIdx.x * 16 + wave * 4 + (lane >> 4);   // i*256+j
  const float4 zv0 = *(const float4*)(z + (size_t)p * 128 + ql * 8);
  const float4 zv1 = *(const float4*)(z + (size_t)p * 128 + ql * 8 + 4);
  float s = zv0.x + zv0.y + zv0.z + zv0.w + zv1.x + zv1.y + zv1.z + zv1.w;
  float sq = zv0.x * zv0.x + zv0.y * zv0.y + zv0.z * zv0.z + zv0.w * zv0.w
           + zv1.x * zv1.x + zv1.y * zv1.y + zv1.z * zv1.z + zv1.w * zv1.w;
  #pragma unroll
  for (int o = 8; o > 0; o >>= 1) { s += __shfl_xor(s, o); sq += __shfl_xor(sq, o); }
  const float mu = s * 0.0078125f;
  const float var = sq * 0.0078125f - mu * mu;
  const float rs = rsqrtf(var + 1e-5f);
  const int c0 = ql * 8;
  float zn[8];
  zn[0] = (zv0.x - mu) * rs * zg[c0 + 0] + zb[c0 + 0];
  zn[1] = (zv0.y - mu) * rs * zg[c0 + 1] + zb[c0 + 1];
  zn[2] = (zv0.z - mu) * rs * zg[c0 + 2] + zb[c0 + 2];
  zn[3] = (zv0.w - mu) * rs * zg[c0 + 3] + zb[c0 + 3];
  zn[4] = (zv1.x - mu) * rs * zg[c0 + 4] + zb[c0 + 4];
  zn[5] = (zv1.y - mu) * rs * zg[c0 + 5] + zb[c0 + 5];
  zn[6] = (zv1.z - mu) * rs * zg[c0 + 6] + zb[c0 + 6];
  zn[7] = (zv1.w - mu) * rs * zg[c0 + 7] + zb[c0 + 7];
  float a[8] = {};
  #pragma unroll
  for (int i = 0; i < 8; ++i) {
    #pragma unroll
    for (int hh = 0; hh < 8; ++hh) a[hh] += zn[i] * wz[(c0 + i) * 8 + hh];
  }
  #pragma unroll
  for (int hh = 0; hh < 8; ++hh) {
    #pragma unroll
    for (int o = 8; o > 0; o >>= 1) a[hh] += __shfl_xor(a[hh], o);
  }
  if (ql == 0) {
    const int i = p >> 8, j = p & 255;
    const int strip = i >> 5, il = i & 31, jt = j >> 5, r = j & 31;
    const int gh = (r >> 2) & 1, qd = r >> 3, c4 = r & 3;
    const int off = (strip * 8 + jt) * 1024 + (gh * 32 + il) * 16 + qd * 4 + c4;
    #pragma unroll
    for (int hh = 0; hh < 8; ++hh) pbp[(size_t)hh * 65536 + off] = a[hh];
  }
}

// ---------------------------------------------------------------------------
// Kernel 2: LayerNorm(m) -> bf16 [32768][256]. Unchanged.
__global__ __launch_bounds__(256) void k_ln_m(
    const float* __restrict__ m, const float* __restrict__ gam,
    const float* __restrict__ bet, u16* __restrict__ mln) {
  const int lane = threadIdx.x & 63;
  const size_t row = (size_t)blockIdx.x * 4 + (threadIdx.x >> 6);
  const float4 xv = *(const float4*)(m + row * 256 + lane * 4);
  float s = xv.x + xv.y + xv.z + xv.w;
  float sq = xv.x * xv.x + xv.y * xv.y + xv.z * xv.z + xv.w * xv.w;
  #pragma unroll
  for (int o = 32; o > 0; o >>= 1) { s += __shfl_xor(s, o); sq += __shfl_xor(sq, o); }
  const float mu = s * 0.00390625f;
  const float var = sq * 0.00390625f - mu * mu;
  const float rs = rsqrtf(var + 1e-5f);
  const int c = lane * 4;
  u16x4 o4;
  o4.x = f2bf((xv.x - mu) * rs * gam[c] + bet[c]);
  o4.y = f2bf((xv.y - mu) * rs * gam[c + 1] + bet[c + 1]);
  o4.z = f2bf((xv.z - mu) * rs * gam[c + 2] + bet[c + 2]);
  o4.w = f2bf((xv.w - mu) * rs * gam[c + 3] + bet[c + 3]);
  *(u16x4*)(mln + row * 256 + c) = o4;
}

// ---------------------------------------------------------------------------
// Kernel 3 (FUSED, fixed): per-(s,h) QKVG projection + attention, one block.
// grid 1024, bid = h*128 + s. GEMM phase: EIGHT chunks of 32 mln rows
// (R=256 total — R10's 4-chunk bug left rows 128..255 uninitialized);
// wave w computes output z=w (Q/K/V/G) as one 32x32 mfma_32x32x16 tile per
// chunk; per-head weight slice (16 frags, 64 VGPR) preloaded once.
// Q/K -> swizzled LDS, V -> lVt, G -> global. Attention phase: R4 body.
__global__ __launch_bounds__(256, 2) void k_fused(
    const u16* __restrict__ mln, const u16* __restrict__ wtp,
    const float* __restrict__ bg, const float* __restrict__ pbp,
    const float* __restrict__ mask, u16* __restrict__ g,
    u16* __restrict__ go) {
  __shared__ u16 lA[32 * 256];     // 16KB chunk staging (swizzled)
  __shared__ u16 lQ[256 * 32];     // 16KB row-major (row-swizzled)
  __shared__ u16 lK[256 * 32];     // 16KB
  __shared__ u16 lVt[32][276];     // 17.25KB V^T padded
  __shared__ float lMb[256];
  __shared__ float lL[4][32];
  const int bid = blockIdx.x;
  const int s = bid & 127, h = bid >> 7;
  const int t = threadIdx.x;
  const int lane = t & 63, wave = t >> 6;
  const int il = lane & 31, gh = lane >> 5;

  // ---- B preload: wave w's weight slice (z=w, cols h*32..h*32+31, K=256)
  const u16* Wb = wtp + (size_t)wave * 65536 + (size_t)(2 * h + (il >> 4)) * 4096
                + gh * 128 + (il & 15) * 8;
  bf16x8 B[16];
  #pragma unroll
  for (int kc = 0; kc < 16; ++kc) B[kc] = *(const bf16x8*)&Wb[kc * 256];
  __builtin_amdgcn_sched_barrier(0);

  lMb[t] = 1e9f * (mask[s * 256 + t] - 1.0f);
  const float bgv = bg[h * 32 + il];
  const size_t mbase = (size_t)s * 65536;

  // ---- GEMM phase: 8 chunks x 32 rows (full R=256)
  #pragma unroll 1
  for (int c = 0; c < 8; ++c) {
    #pragma unroll
    for (int i = 0; i < 4; ++i) {
      const int r = i * 8 + (t >> 5);
      const int cc = (t & 31) * 8;
      *(u16x8*)((char*)lA + ((r * 512 + cc * 2) ^ ((r & 7) << 4))) =
          *(const u16x8*)&mln[mbase + (size_t)(c * 32 + r) * 256 + cc];
    }
    __syncthreads();
    f32x16 acc = {};
    #pragma unroll
    for (int kc = 0; kc < 16; ++kc) {
      const bf16x8 af = *(const bf16x8*)((const char*)lA +
          ((il * 512 + (kc * 16 + gh * 8) * 2) ^ ((il & 7) << 4)));
      acc = __builtin_amdgcn_mfma_f32_32x32x16_bf16(af, B[kc], acc, 0, 0, 0);
    }
    // D[row][col=il], row = (reg&3) + 8*(reg>>2) + 4*gh  (within chunk)
    if (wave == 0) {         // Q (scaled)
      #pragma unroll
      for (int reg = 0; reg < 16; ++reg) {
        const int R = c * 32 + (reg & 3) + 8 * (reg >> 2) + 4 * gh;
        *(u16*)((char*)lQ + ((R * 64 + il * 2) ^ ((R & 7) << 4))) =
            f2bf(acc[reg] * 0.17677669529663687f);
      }
    } else if (wave == 1) {  // K
      #pragma unroll
      for (int reg = 0; reg < 16; ++reg) {
        const int R = c * 32 + (reg & 3) + 8 * (reg >> 2) + 4 * gh;
        *(u16*)((char*)lK + ((R * 64 + il * 2) ^ ((R & 7) << 4))) = f2bf(acc[reg]);
      }
    } else if (wave == 2) {  // V -> V^T
      #pragma unroll
      for (int reg = 0; reg < 16; ++reg) {
        const int R = c * 32 + (reg & 3) + 8 * (reg >> 2) + 4 * gh;
        lVt[il][R] = f2bf(acc[reg]);
      }
    } else {                 // G = sigmoid(x + bg) -> global
      #pragma unroll
      for (int reg = 0; reg < 16; ++reg) {
        const int R = c * 32 + (reg & 3) + 8 * (reg >> 2) + 4 * gh;
        const float x = acc[reg] + bgv;
        g[(size_t)(s * 256 + R) * 256 + h * 32 + il] =
            f2bf(1.0f / (1.0f + __expf(-x)));
      }
    }
    __syncthreads();
  }

  // ---- Attention phase (R4 body; Q/K from LDS)
  #pragma unroll 1
  for (int strip = 0; strip < 2; ++strip) {
    const int i0 = wave * 64 + strip * 32;
    bf16x8 qf[2];
    #pragma unroll
    for (int kk = 0; kk < 2; ++kk) {
      const int row = i0 + il;
      qf[kk] = *(const bf16x8*)((const char*)lQ +
          ((row * 64 + (kk * 16 + gh * 8) * 2) ^ ((row & 7) << 4)));
    }
    const float* pbt = pbp + ((size_t)h * 8 + (i0 >> 5)) * 8192 + lane * 16;

    f32x16 oacc0 = {}, oacc1 = {};
    float s0 = 0.f, s1 = 0.f, s2 = 0.f, s3 = 0.f;

    #pragma unroll 2
    for (int jt = 0; jt < 8; ++jt) {
      const float* pl = pbt + jt * 1024;
      f32x16 c;
      #pragma unroll
      for (int qd = 0; qd < 4; ++qd) {
        const f32x4 pbq = *(const f32x4*)&pl[qd * 4];
        const int jb = jt * 32 + qd * 8 + gh * 4;
        #pragma unroll
        for (int c4 = 0; c4 < 4; ++c4)
          c[qd * 4 + c4] = pbq[c4] + lMb[jb + c4] - 16.0f;
      }
      const int krow = jt * 32 + il;
      const bf16x8 kf0 = *(const bf16x8*)((const char*)lK +
          ((krow * 64 + (gh * 8) * 2) ^ ((krow & 7) << 4)));
      const bf16x8 kf1 = *(const bf16x8*)((const char*)lK +
          ((krow * 64 + (16 + gh * 8) * 2) ^ ((krow & 7) << 4)));
      c = __builtin_amdgcn_mfma_f32_32x32x16_bf16(kf0, qf[0], c, 0, 0, 0);
      c = __builtin_amdgcn_mfma_f32_32x32x16_bf16(kf1, qf[1], c, 0, 0, 0);
      union PK { __bf16 h[4]; uint2 u; } pk[4];
      #pragma unroll
      for (int qd = 0; qd < 4; ++qd) {
        const float p0 = __expf(c[qd * 4 + 0]);
        const float p1 = __expf(c[qd * 4 + 1]);
        const float p2 = __expf(c[qd * 4 + 2]);
        const float p3 = __expf(c[qd * 4 + 3]);
        s0 += p0; s1 += p1; s2 += p2; s3 += p3;
        pk[qd].h[0] = (__bf16)p0; pk[qd].h[1] = (__bf16)p1;
        pk[qd].h[2] = (__bf16)p2; pk[qd].h[3] = (__bf16)p3;
      }
      const uint2 sA = gh ? pk[0].u : pk[1].u;
      uint2 rA; rA.x = __shfl_xor(sA.x, 32); rA.y = __shfl_xor(sA.y, 32);
      const uint2 sB = gh ? pk[2].u : pk[3].u;
      uint2 rB; rB.x = __shfl_xor(sB.x, 32); rB.y = __shfl_xor(sB.y, 32);
      union FR { uint2 u2[2]; bf16x8 v; } fa0, fa1;
      fa0.u2[0] = gh ? rA : pk[0].u;
      fa0.u2[1] = gh ? pk[1].u : rA;
      fa1.u2[0] = gh ? rB : pk[2].u;
      fa1.u2[1] = gh ? pk[3].u : rB;
      const bf16x8 vf0 = *(const bf16x8*)&lVt[il][jt * 32 + gh * 8];
      const bf16x8 vf1 = *(const bf16x8*)&lVt[il][jt * 32 + 16 + gh * 8];
      oacc0 = __builtin_amdgcn_mfma_f32_32x32x16_bf16(fa0.v, vf0, oacc0, 0, 0, 0);
      oacc1 = __builtin_amdgcn_mfma_f32_32x32x16_bf16(fa1.v, vf1, oacc1, 0, 0, 0);
    }

    float lsum = (s0 + s1) + (s2 + s3);
    lsum += __shfl_xor(lsum, 32);
    if (lane < 32) lL[wave][il] = 1.0f / lsum;

    #pragma unroll
    for (int qd = 0; qd < 4; ++qd) {
      const f32x4 invq = *(const f32x4*)&lL[wave][qd * 8 + gh * 4];
      #pragma unroll
      for (int c4 = 0; c4 < 4; ++c4) {
        const int iloc = qd * 8 + gh * 4 + c4;
        const size_t row = (size_t)s * 256 + i0 + iloc;
        const int col = h * 32 + il;
        const float ov = (oacc0[qd * 4 + c4] + oacc1[qd * 4 + c4]) * invq[c4];
        go[row * 256 + col] = f2bf(bf2f(g[row * 256 + col]) * ov);
      }
    }
  }
}

// ---------------------------------------------------------------------------
// Kernel 5: out = go @ wo + bo. grid 1024: 32 rows x 256 cols. Unchanged R9.
__global__ __launch_bounds__(256, 4) void k_gemm_out(
    const u16* __restrict__ go, const u16* __restrict__ wop,
    const float* __restrict__ bo, float* __restrict__ out) {
  __shared__ u16 lA[32 * 256];
  const int t = threadIdx.x;
  const size_t row0 = (size_t)blockIdx.x * 32;
  const int lane = t & 63, wave = t >> 6;
  const u16* Wz = wop + (size_t)wave * 16384 + (size_t)lane * 8;
  u16x8 areg[4];
  #pragma unroll
  for (int i = 0; i < 4; ++i)
    areg[i] = *(const u16x8*)&go[(row0 + i * 8 + (t >> 5)) * 256 + (t & 31) * 8];
  bf16x8 B[4][4];
  #pragma unroll
  for (int kc = 0; kc < 4; ++kc) {
    #pragma unroll
    for (int nn = 0; nn < 4; ++nn)
      B[kc][nn] = *(const bf16x8*)&Wz[nn * 4096 + kc * 512];
  }
  __builtin_amdgcn_sched_barrier(0);
  #pragma unroll
  for (int i = 0; i < 4; ++i) {
    const int r = i * 8 + (t >> 5);
    const int c = (t & 31) * 8;
    *(u16x8*)((char*)lA + ((r * 512 + c * 2) ^ ((r & 7) << 4))) = areg[i];
  }
  __syncthreads();
  const int lrow = lane & 15, lg = lane >> 4;
  f32x4 acc[2][4] = {};
  #pragma unroll
  for (int kc = 0; kc < 4; ++kc) {
    bf16x8 af[2];
    #pragma unroll
    for (int mm = 0; mm < 2; ++mm) {
      const int row = mm * 16 + lrow;
      af[mm] = *(const bf16x8*)((const char*)lA +
          ((row * 512 + kc * 64 + lg * 16) ^ ((row & 7) << 4)));
    }
    #pragma unroll
    for (int mm = 0; mm < 2; ++mm) {
      #pragma unroll
      for (int nn = 0; nn < 4; ++nn)
        acc[mm][nn] = __builtin_amdgcn_mfma_f32_16x16x32_bf16(
            af[mm], B[kc][nn], acc[mm][nn], 0, 0, 0);
    }
  }
  #pragma unroll
  for (int kc = 0; kc < 4; ++kc) {
    #pragma unroll
    for (int nn = 0; nn < 4; ++nn)
      B[kc][nn] = *(const bf16x8*)&Wz[nn * 4096 + (kc + 4) * 512];
  }
  __builtin_amdgcn_sched_barrier(0);
  #pragma unroll
  for (int kc = 0; kc < 4; ++kc) {
    bf16x8 af[2];
    #pragma unroll
    for (int mm = 0; mm < 2; ++mm) {
      const int row = mm * 16 + lrow;
      af[mm] = *(const bf16x8*)((const char*)lA +
          ((row * 512 + (kc + 4) * 64 + lg * 16) ^ ((row & 7) << 4)));
    }
    #pragma unroll
    for (int mm = 0; mm < 2; ++mm) {
      #pragma unroll
      for (int nn = 0; nn < 4; ++nn)
        acc[mm][nn] = __builtin_amdgcn_mfma_f32_16x16x32_bf16(
            af[mm], B[kc][nn], acc[mm][nn], 0, 0, 0);
    }
  }
  const int wc = wave * 64, lg4 = lg * 4;
  #pragma unroll
  for (int mm = 0; mm < 2; ++mm) {
    #pragma unroll
    for (int nn = 0; nn < 4; ++nn) {
      const int col = wc + nn * 16 + lrow;
      #pragma unroll
      for (int jr = 0; jr < 4; ++jr) {
        const size_t row = row0 + mm * 16 + lg4 + jr;
        out[row * 256 + col] = acc[mm][nn][jr] + bo[col];
      }
    }
  }
}

// ---------------------------------------------------------------------------
extern "C" void kernel_launch(void* const* d_in, const int* in_sizes, int n_in,
                              void* d_out, int out_size, void* d_ws, size_t ws_size,
                              hipStream_t stream) {
  const float* m      = (const float*)d_in[0];
  const float* z      = (const float*)d_in[1];
  const float* mask   = (const float*)d_in[2];
  const float* ln_m_g = (const float*)d_in[3];
  const float* ln_m_b = (const float*)d_in[4];
  const float* ln_z_g = (const float*)d_in[5];
  const float* ln_z_b = (const float*)d_in[6];
  const float* w_z    = (const float*)d_in[7];
  const float* wq     = (const float*)d_in[8];
  const float* wk     = (const float*)d_in[9];
  const float* wv     = (const float*)d_in[10];
  const float* wg     = (const float*)d_in[11];
  const float* bg     = (const float*)d_in[12];
  const float* wo     = (const float*)d_in[13];
  const float* bo     = (const float*)d_in[14];
  float* out = (float*)d_out;

  char* w = (char*)d_ws;
  u16* wtp   = (u16*)w;   w += (size_t)5 * 65536 * 2;
  float* pbp = (float*)w; w += (size_t)8 * 65536 * 4;
  u16* mln   = (u16*)w;   w += (size_t)32768 * 256 * 2;
  u16* gow   = (u16*)w;   w += (size_t)32768 * 256 * 2;   // g*o
  u16* gw    = (u16*)w;   w += (size_t)32768 * 256 * 2;   // gate

  k_prep_w   <<<80, 256, 0, stream>>>(wq, wk, wv, wg, wo, wtp);
  k_pair_bias<<<4096, 256, 0, stream>>>(z, ln_z_g, ln_z_b, w_z, pbp);
  k_ln_m     <<<8192, 256, 0, stream>>>(m, ln_m_g, ln_m_b, mln);
  k_fused    <<<1024, 256, 0, stream>>>(mln, wtp, bg, pbp, mask, gw, gow);
  k_gemm_out <<<1024, 256, 0, stream>>>(gow, wtp + (size_t)4 * 65536, bo, out);
}

// Round 12
// 114.390 us; speedup vs baseline: 1.2738x; 1.0744x over previous
//
#include <hip/hip_runtime.h>
#include <hip/hip_bf16.h>

typedef unsigned short u16;
typedef __bf16 bf16x8 __attribute__((ext_vector_type(8)));
typedef float f32x4 __attribute__((ext_vector_type(4)));
typedef float f32x16 __attribute__((ext_vector_type(16)));
typedef unsigned short u16x8 __attribute__((ext_vector_type(8)));
typedef unsigned short u16x4 __attribute__((ext_vector_type(4)));

// S=128, R=256, CM=256, CZ=128, H=8, HD=32
#define LOG2E 1.4426950408889634f

__device__ __forceinline__ u16 f2b(float f) {          // native HW bf16 cvt (RNE)
  union { __bf16 b; u16 u; } v; v.b = (__bf16)f; return v.u;
}
__device__ __forceinline__ float bf2f(u16 u) {
  union { unsigned u; float f; } v; v.u = ((unsigned)u) << 16;
  return v.f;
}

// ---------------------------------------------------------------------------
// Kernel 0 (MERGED pre-pass): blocks [0,80) = weight pack; [80,4176) =
// pair bias (pre-scaled by LOG2E); [4176,12368) = LayerNorm(m)->bf16.
// Independent work made concurrent in one launch.
__global__ __launch_bounds__(256) void k_pre(
    const float* __restrict__ wq, const float* __restrict__ wk,
    const float* __restrict__ wv, const float* __restrict__ wg,
    const float* __restrict__ wo, u16* __restrict__ wtp,
    const float* __restrict__ z, const float* __restrict__ zg,
    const float* __restrict__ zb, const float* __restrict__ wz,
    float* __restrict__ pbp,
    const float* __restrict__ m, const float* __restrict__ gam,
    const float* __restrict__ bet, u16* __restrict__ mln) {
  __shared__ float lt[64][68];
  const int b = blockIdx.x;
  const int t = threadIdx.x;
  if (b < 80) {
    // ---- weight fp32 [k][n] -> bf16 packed MFMA B-fragment order
    const int widx = b >> 4;
    const int tid = b & 15;
    const int ri = (tid >> 2) * 64, ci = (tid & 3) * 64;
    const float* src = (widx == 0) ? wq : (widx == 1) ? wk : (widx == 2) ? wv
                      : (widx == 3) ? wg : wo;
    {
      const int r = t >> 2;
      #pragma unroll
      for (int i = 0; i < 4; ++i) {
        const int c = (t & 3) * 16 + i * 4;
        *(float4*)&lt[r][c] = *(const float4*)&src[(ri + r) * 256 + ci + c];
      }
    }
    __syncthreads();
    #pragma unroll
    for (int cc = 0; cc < 2; ++cc) {
      const int c = t + cc * 256;
      const int kb = c >> 8, cb = (c >> 6) & 3, lg = (c >> 4) & 3, lr = c & 15;
      u16x8 o;
      #pragma unroll
      for (int j = 0; j < 8; ++j) o[j] = f2b(lt[kb * 32 + lg * 8 + j][cb * 16 + lr]);
      const size_t idx = (size_t)widx * 65536 + (size_t)((ci >> 4) + cb) * 4096
                       + (size_t)((ri >> 5) + kb) * 512 + (size_t)(lg * 16 + lr) * 8;
      *(u16x8*)&wtp[idx] = o;
    }
  } else if (b < 4176) {
    // ---- pair bias -> permuted pbp, PRE-SCALED by LOG2E
    const int lane = t & 63, wave = t >> 6;
    const int ql = lane & 15;
    const int p = (b - 80) * 16 + wave * 4 + (lane >> 4);
    const float4 zv0 = *(const float4*)(z + (size_t)p * 128 + ql * 8);
    const float4 zv1 = *(const float4*)(z + (size_t)p * 128 + ql * 8 + 4);
    float s = zv0.x + zv0.y + zv0.z + zv0.w + zv1.x + zv1.y + zv1.z + zv1.w;
    float sq = zv0.x * zv0.x + zv0.y * zv0.y + zv0.z * zv0.z + zv0.w * zv0.w
             + zv1.x * zv1.x + zv1.y * zv1.y + zv1.z * zv1.z + zv1.w * zv1.w;
    #pragma unroll
    for (int o = 8; o > 0; o >>= 1) { s += __shfl_xor(s, o); sq += __shfl_xor(sq, o); }
    const float mu = s * 0.0078125f;
    const float var = sq * 0.0078125f - mu * mu;
    const float rs = rsqrtf(var + 1e-5f);
    const int c0 = ql * 8;
    float zn[8];
    zn[0] = (zv0.x - mu) * rs * zg[c0 + 0] + zb[c0 + 0];
    zn[1] = (zv0.y - mu) * rs * zg[c0 + 1] + zb[c0 + 1];
    zn[2] = (zv0.z - mu) * rs * zg[c0 + 2] + zb[c0 + 2];
    zn[3] = (zv0.w - mu) * rs * zg[c0 + 3] + zb[c0 + 3];
    zn[4] = (zv1.x - mu) * rs * zg[c0 + 4] + zb[c0 + 4];
    zn[5] = (zv1.y - mu) * rs * zg[c0 + 5] + zb[c0 + 5];
    zn[6] = (zv1.z - mu) * rs * zg[c0 + 6] + zb[c0 + 6];
    zn[7] = (zv1.w - mu) * rs * zg[c0 + 7] + zb[c0 + 7];
    float a[8] = {};
    #pragma unroll
    for (int i = 0; i < 8; ++i) {
      #pragma unroll
      for (int hh = 0; hh < 8; ++hh) a[hh] += zn[i] * wz[(c0 + i) * 8 + hh];
    }
    #pragma unroll
    for (int hh = 0; hh < 8; ++hh) {
      #pragma unroll
      for (int o = 8; o > 0; o >>= 1) a[hh] += __shfl_xor(a[hh], o);
    }
    if (ql == 0) {
      const int i = p >> 8, j = p & 255;
      const int strip = i >> 5, il = i & 31, jt = j >> 5, r = j & 31;
      const int gh = (r >> 2) & 1, qd = r >> 3, c4 = r & 3;
      const int off = (strip * 8 + jt) * 1024 + (gh * 32 + il) * 16 + qd * 4 + c4;
      #pragma unroll
      for (int hh = 0; hh < 8; ++hh)
        pbp[(size_t)hh * 65536 + off] = a[hh] * LOG2E;
    }
  } else {
    // ---- LayerNorm(m) -> bf16
    const int lane = t & 63;
    const size_t row = (size_t)(b - 4176) * 4 + (t >> 6);
    const float4 xv = *(const float4*)(m + row * 256 + lane * 4);
    float s = xv.x + xv.y + xv.z + xv.w;
    float sq = xv.x * xv.x + xv.y * xv.y + xv.z * xv.z + xv.w * xv.w;
    #pragma unroll
    for (int o = 32; o > 0; o >>= 1) { s += __shfl_xor(s, o); sq += __shfl_xor(sq, o); }
    const float mu = s * 0.00390625f;
    const float var = sq * 0.00390625f - mu * mu;
    const float rs = rsqrtf(var + 1e-5f);
    const int c = lane * 4;
    u16x4 o4;
    o4.x = f2b((xv.x - mu) * rs * gam[c] + bet[c]);
    o4.y = f2b((xv.y - mu) * rs * gam[c + 1] + bet[c + 1]);
    o4.z = f2b((xv.z - mu) * rs * gam[c + 2] + bet[c + 2]);
    o4.w = f2b((xv.w - mu) * rs * gam[c + 3] + bet[c + 3]);
    *(u16x4*)(mln + row * 256 + c) = o4;
  }
}

// ---------------------------------------------------------------------------
// Kernel 1 (FUSED v2): per-(s,h) QKVG projection + attention.
// Changes vs R11: native bf16 cvt; log2-domain softmax (pbp/mask/q pre-scaled,
// shift folded into lMb, exp2f); g kept in registers then parked in dead lA
// (no global g round-trip, no per-chunk store drains); mln chunk prefetch
// issued after mid-barrier (latency hides under MFMA), loop fully unrolled;
// GEMM MFMA split into 2 chains.
__global__ __launch_bounds__(256, 2) void k_fused(
    const u16* __restrict__ mln, const u16* __restrict__ wtp,
    const float* __restrict__ bg, const float* __restrict__ pbp,
    const float* __restrict__ mask, u16* __restrict__ go) {
  __shared__ u16 lA[32 * 256];     // chunk staging; later: g[256][32] bf16
  __shared__ u16 lQ[256 * 32];
  __shared__ u16 lK[256 * 32];
  __shared__ u16 lVt[32][276];
  __shared__ float lMb[256];
  __shared__ float lL[4][32];
  const int bid = blockIdx.x;
  const int s = bid & 127, h = bid >> 7;
  const int t = threadIdx.x;
  const int lane = t & 63, wave = t >> 6;
  const int il = lane & 31, gh = lane >> 5;

  // B preload: wave w's weight slice (z=w, cols h*32..+31, K=256)
  const u16* Wb = wtp + (size_t)wave * 65536 + (size_t)(2 * h + (il >> 4)) * 4096
                + gh * 128 + (il & 15) * 8;
  bf16x8 B[16];
  #pragma unroll
  for (int kc = 0; kc < 16; ++kc) B[kc] = *(const bf16x8*)&Wb[kc * 256];
  __builtin_amdgcn_sched_barrier(0);

  lMb[t] = (LOG2E * 1e9f) * (mask[s * 256 + t] - 1.0f) - 24.0f;  // log2-domain + shift
  const float bgv = bg[h * 32 + il];
  const size_t mbase = (size_t)s * 65536;

  u16x8 areg[4];
  #pragma unroll
  for (int i = 0; i < 4; ++i)
    areg[i] = *(const u16x8*)&mln[mbase + (size_t)(i * 8 + (t >> 5)) * 256 + (t & 31) * 8];
  unsigned gpk[64];   // wave3: packed sigmoid bf16 pairs (static idx, full unroll)

  // ---- GEMM phase: 8 chunks x 32 rows, fully unrolled
  #pragma unroll
  for (int c = 0; c < 8; ++c) {
    #pragma unroll
    for (int i = 0; i < 4; ++i) {
      const int r = i * 8 + (t >> 5);
      *(u16x8*)((char*)lA + ((r * 512 + (t & 31) * 16) ^ ((r & 7) << 4))) = areg[i];
    }
    __syncthreads();
    if (c < 7) {   // prefetch next chunk AFTER barrier: drains under MFMA
      #pragma unroll
      for (int i = 0; i < 4; ++i)
        areg[i] = *(const u16x8*)&mln[mbase +
            (size_t)((c + 1) * 32 + i * 8 + (t >> 5)) * 256 + (t & 31) * 8];
      __builtin_amdgcn_sched_barrier(0);
    }
    f32x16 a0 = {}, a1 = {};
    #pragma unroll
    for (int kc = 0; kc < 16; kc += 2) {
      const bf16x8 af0 = *(const bf16x8*)((const char*)lA +
          ((il * 512 + (kc * 16 + gh * 8) * 2) ^ ((il & 7) << 4)));
      const bf16x8 af1 = *(const bf16x8*)((const char*)lA +
          ((il * 512 + ((kc + 1) * 16 + gh * 8) * 2) ^ ((il & 7) << 4)));
      a0 = __builtin_amdgcn_mfma_f32_32x32x16_bf16(af0, B[kc], a0, 0, 0, 0);
      a1 = __builtin_amdgcn_mfma_f32_32x32x16_bf16(af1, B[kc + 1], a1, 0, 0, 0);
    }
    const f32x16 acc = a0 + a1;
    if (wave == 0) {         // Q scaled by (1/sqrt32)*LOG2E (log2-domain QK)
      #pragma unroll
      for (int reg = 0; reg < 16; ++reg) {
        const int R = c * 32 + (reg & 3) + 8 * (reg >> 2) + 4 * gh;
        *(u16*)((char*)lQ + ((R * 64 + il * 2) ^ ((R & 7) << 4))) =
            f2b(acc[reg] * (0.17677669529663687f * LOG2E));
      }
    } else if (wave == 1) {  // K
      #pragma unroll
      for (int reg = 0; reg < 16; ++reg) {
        const int R = c * 32 + (reg & 3) + 8 * (reg >> 2) + 4 * gh;
        *(u16*)((char*)lK + ((R * 64 + il * 2) ^ ((R & 7) << 4))) = f2b(acc[reg]);
      }
    } else if (wave == 2) {  // V -> V^T
      #pragma unroll
      for (int reg = 0; reg < 16; ++reg) {
        const int R = c * 32 + (reg & 3) + 8 * (reg >> 2) + 4 * gh;
        lVt[il][R] = f2b(acc[reg]);
      }
    } else {                 // G = sigmoid(x+bg) kept in registers
      #pragma unroll
      for (int r4 = 0; r4 < 8; ++r4) {
        const float x0 = acc[2 * r4] + bgv;
        const float x1 = acc[2 * r4 + 1] + bgv;
        const u16 u0 = f2b(1.0f / (1.0f + __expf(-x0)));
        const u16 u1 = f2b(1.0f / (1.0f + __expf(-x1)));
        gpk[c * 8 + r4] = (unsigned)u0 | ((unsigned)u1 << 16);
      }
    }
    __syncthreads();
  }

  // ---- park g in lA (dead after GEMM phase): g_lds[row][il] bf16
  if (wave == 3) {
    #pragma unroll
    for (int c = 0; c < 8; ++c) {
      #pragma unroll
      for (int r4 = 0; r4 < 8; ++r4) {
        const int R0 = c * 32 + ((2 * r4) & 3) + 8 * (r4 >> 1) + 4 * gh;
        const unsigned p = gpk[c * 8 + r4];
        lA[R0 * 32 + il] = (u16)p;
        lA[(R0 + 1) * 32 + il] = (u16)(p >> 16);
      }
    }
  }
  __syncthreads();

  // ---- Attention phase (log2-domain: p = exp2(s' + lMb))
  #pragma unroll 1
  for (int strip = 0; strip < 2; ++strip) {
    const int i0 = wave * 64 + strip * 32;
    bf16x8 qf[2];
    #pragma unroll
    for (int kk = 0; kk < 2; ++kk) {
      const int row = i0 + il;
      qf[kk] = *(const bf16x8*)((const char*)lQ +
          ((row * 64 + (kk * 16 + gh * 8) * 2) ^ ((row & 7) << 4)));
    }
    const float* pbt = pbp + ((size_t)h * 8 + (i0 >> 5)) * 8192 + lane * 16;

    f32x16 oacc0 = {}, oacc1 = {};
    float s0 = 0.f, s1 = 0.f, s2 = 0.f, s3 = 0.f;

    #pragma unroll 2
    for (int jt = 0; jt < 8; ++jt) {
      const float* pl = pbt + jt * 1024;
      f32x16 c;
      #pragma unroll
      for (int qd = 0; qd < 4; ++qd) {
        const f32x4 pbq = *(const f32x4*)&pl[qd * 4];
        const int jb = jt * 32 + qd * 8 + gh * 4;
        #pragma unroll
        for (int c4 = 0; c4 < 4; ++c4)
          c[qd * 4 + c4] = pbq[c4] + lMb[jb + c4];
      }
      const int krow = jt * 32 + il;
      const bf16x8 kf0 = *(const bf16x8*)((const char*)lK +
          ((krow * 64 + (gh * 8) * 2) ^ ((krow & 7) << 4)));
      const bf16x8 kf1 = *(const bf16x8*)((const char*)lK +
          ((krow * 64 + (16 + gh * 8) * 2) ^ ((krow & 7) << 4)));
      c = __builtin_amdgcn_mfma_f32_32x32x16_bf16(kf0, qf[0], c, 0, 0, 0);
      c = __builtin_amdgcn_mfma_f32_32x32x16_bf16(kf1, qf[1], c, 0, 0, 0);
      union PK { __bf16 h[4]; uint2 u; } pk[4];
      #pragma unroll
      for (int qd = 0; qd < 4; ++qd) {
        const float p0 = exp2f(c[qd * 4 + 0]);
        const float p1 = exp2f(c[qd * 4 + 1]);
        const float p2 = exp2f(c[qd * 4 + 2]);
        const float p3 = exp2f(c[qd * 4 + 3]);
        s0 += p0; s1 += p1; s2 += p2; s3 += p3;
        pk[qd].h[0] = (__bf16)p0; pk[qd].h[1] = (__bf16)p1;
        pk[qd].h[2] = (__bf16)p2; pk[qd].h[3] = (__bf16)p3;
      }
      const uint2 sA = gh ? pk[0].u : pk[1].u;
      uint2 rA; rA.x = __shfl_xor(sA.x, 32); rA.y = __shfl_xor(sA.y, 32);
      const uint2 sB = gh ? pk[2].u : pk[3].u;
      uint2 rB; rB.x = __shfl_xor(sB.x, 32); rB.y = __shfl_xor(sB.y, 32);
      union FR { uint2 u2[2]; bf16x8 v; } fa0, fa1;
      fa0.u2[0] = gh ? rA : pk[0].u;
      fa0.u2[1] = gh ? pk[1].u : rA;
      fa1.u2[0] = gh ? rB : pk[2].u;
      fa1.u2[1] = gh ? pk[3].u : rB;
      const bf16x8 vf0 = *(const bf16x8*)&lVt[il][jt * 32 + gh * 8];
      const bf16x8 vf1 = *(const bf16x8*)&lVt[il][jt * 32 + 16 + gh * 8];
      oacc0 = __builtin_amdgcn_mfma_f32_32x32x16_bf16(fa0.v, vf0, oacc0, 0, 0, 0);
      oacc1 = __builtin_amdgcn_mfma_f32_32x32x16_bf16(fa1.v, vf1, oacc1, 0, 0, 0);
    }

    float lsum = (s0 + s1) + (s2 + s3);
    lsum += __shfl_xor(lsum, 32);
    if (lane < 32) lL[wave][il] = 1.0f / lsum;

    #pragma unroll
    for (int qd = 0; qd < 4; ++qd) {
      const f32x4 invq = *(const f32x4*)&lL[wave][qd * 8 + gh * 4];
      #pragma unroll
      for (int c4 = 0; c4 < 4; ++c4) {
        const int iloc = qd * 8 + gh * 4 + c4;
        const size_t row = (size_t)s * 256 + i0 + iloc;
        const int col = h * 32 + il;
        const float ov = (oacc0[qd * 4 + c4] + oacc1[qd * 4 + c4]) * invq[c4];
        const float gv = bf2f(lA[(i0 + iloc) * 32 + il]);
        go[row * 256 + col] = f2b(gv * ov);
      }
    }
  }
}

// ---------------------------------------------------------------------------
// Kernel 2: out = go @ wo + bo. grid 1024: 32 rows x 256 cols. Unchanged R9.
__global__ __launch_bounds__(256, 4) void k_gemm_out(
    const u16* __restrict__ go, const u16* __restrict__ wop,
    const float* __restrict__ bo, float* __restrict__ out) {
  __shared__ u16 lA[32 * 256];
  const int t = threadIdx.x;
  const size_t row0 = (size_t)blockIdx.x * 32;
  const int lane = t & 63, wave = t >> 6;
  const u16* Wz = wop + (size_t)wave * 16384 + (size_t)lane * 8;
  u16x8 areg[4];
  #pragma unroll
  for (int i = 0; i < 4; ++i)
    areg[i] = *(const u16x8*)&go[(row0 + i * 8 + (t >> 5)) * 256 + (t & 31) * 8];
  bf16x8 B[4][4];
  #pragma unroll
  for (int kc = 0; kc < 4; ++kc) {
    #pragma unroll
    for (int nn = 0; nn < 4; ++nn)
      B[kc][nn] = *(const bf16x8*)&Wz[nn * 4096 + kc * 512];
  }
  __builtin_amdgcn_sched_barrier(0);
  #pragma unroll
  for (int i = 0; i < 4; ++i) {
    const int r = i * 8 + (t >> 5);
    const int c = (t & 31) * 8;
    *(u16x8*)((char*)lA + ((r * 512 + c * 2) ^ ((r & 7) << 4))) = areg[i];
  }
  __syncthreads();
  const int lrow = lane & 15, lg = lane >> 4;
  f32x4 acc[2][4] = {};
  #pragma unroll
  for (int kc = 0; kc < 4; ++kc) {
    bf16x8 af[2];
    #pragma unroll
    for (int mm = 0; mm < 2; ++mm) {
      const int row = mm * 16 + lrow;
      af[mm] = *(const bf16x8*)((const char*)lA +
          ((row * 512 + kc * 64 + lg * 16) ^ ((row & 7) << 4)));
    }
    #pragma unroll
    for (int mm = 0; mm < 2; ++mm) {
      #pragma unroll
      for (int nn = 0; nn < 4; ++nn)
        acc[mm][nn] = __builtin_amdgcn_mfma_f32_16x16x32_bf16(
            af[mm], B[kc][nn], acc[mm][nn], 0, 0, 0);
    }
  }
  #pragma unroll
  for (int kc = 0; kc < 4; ++kc) {
    #pragma unroll
    for (int nn = 0; nn < 4; ++nn)
      B[kc][nn] = *(const bf16x8*)&Wz[nn * 4096 + (kc + 4) * 512];
  }
  __builtin_amdgcn_sched_barrier(0);
  #pragma unroll
  for (int kc = 0; kc < 4; ++kc) {
    bf16x8 af[2];
    #pragma unroll
    for (int mm = 0; mm < 2; ++mm) {
      const int row = mm * 16 + lrow;
      af[mm] = *(const bf16x8*)((const char*)lA +
          ((row * 512 + (kc + 4) * 64 + lg * 16) ^ ((row & 7) << 4)));
    }
    #pragma unroll
    for (int mm = 0; mm < 2; ++mm) {
      #pragma unroll
      for (int nn = 0; nn < 4; ++nn)
        acc[mm][nn] = __builtin_amdgcn_mfma_f32_16x16x32_bf16(
            af[mm], B[kc][nn], acc[mm][nn], 0, 0, 0);
    }
  }
  const int wc = wave * 64, lg4 = lg * 4;
  #pragma unroll
  for (int mm = 0; mm < 2; ++mm) {
    #pragma unroll
    for (int nn = 0; nn < 4; ++nn) {
      const int col = wc + nn * 16 + lrow;
      #pragma unroll
      for (int jr = 0; jr < 4; ++jr) {
        const size_t row = row0 + mm * 16 + lg4 + jr;
        out[row * 256 + col] = acc[mm][nn][jr] + bo[col];
      }
    }
  }
}

// ---------------------------------------------------------------------------
extern "C" void kernel_launch(void* const* d_in, const int* in_sizes, int n_in,
                              void* d_out, int out_size, void* d_ws, size_t ws_size,
                              hipStream_t stream) {
  const float* m      = (const float*)d_in[0];
  const float* z      = (const float*)d_in[1];
  const float* mask   = (const float*)d_in[2];
  const float* ln_m_g = (const float*)d_in[3];
  const float* ln_m_b = (const float*)d_in[4];
  const float* ln_z_g = (const float*)d_in[5];
  const float* ln_z_b = (const float*)d_in[6];
  const float* w_z    = (const float*)d_in[7];
  const float* wq     = (const float*)d_in[8];
  const float* wk     = (const float*)d_in[9];
  const float* wv     = (const float*)d_in[10];
  const float* wg     = (const float*)d_in[11];
  const float* bg     = (const float*)d_in[12];
  const float* wo     = (const float*)d_in[13];
  const float* bo     = (const float*)d_in[14];
  float* out = (float*)d_out;

  char* w = (char*)d_ws;
  u16* wtp   = (u16*)w;   w += (size_t)5 * 65536 * 2;
  float* pbp = (float*)w; w += (size_t)8 * 65536 * 4;
  u16* mln   = (u16*)w;   w += (size_t)32768 * 256 * 2;
  u16* gow   = (u16*)w;   w += (size_t)32768 * 256 * 2;

  k_pre      <<<12368, 256, 0, stream>>>(wq, wk, wv, wg, wo, wtp,
                                         z, ln_z_g, ln_z_b, w_z, pbp,
                                         m, ln_m_g, ln_m_b, mln);
  k_fused    <<<1024, 256, 0, stream>>>(mln, wtp, bg, pbp, mask, gow);
  k_gemm_out <<<1024, 256, 0, stream>>>(gow, wtp + (size_t)4 * 65536, bo, out);
}